// Round 4
// baseline (130.040 us; speedup 1.0000x reference)
//
#include <hip/hip_runtime.h>
#include <math.h>

// Problem constants (from reference)
#define BB    8
#define HMC   2
#define HW    41344           // 152*272
#define EMBD  128
#define KOBJ  128
#define KG    8192
#define NID0  500
#define NID1  300
#define TE    16              // entries per logits tile
#define GRID  512             // co-resident: launch_bounds(256,2) -> 2 blocks/CU x 256 CU

// d_ws layout (words):
//   [0] pos_loss [1] neg_loss [2] num_pos [3] num_wh [4] num_off [5] mask_sum
//   [6] nll0 [7] nll1  (float accumulators)
//   [8] cnt0 [9] cnt1  (int)  [10] done-counter  [11] barrier counter
//   [16 .. 16+KG)  idx0    [16+KG .. 16+2KG)  idx1
// (memset node zeroes words 0..15 each replay)

__device__ __forceinline__ float wave_sum(float v) {
    #pragma unroll
    for (int o = 32; o > 0; o >>= 1) v += __shfl_down(v, o, 64);
    return v;
}
__device__ __forceinline__ float aread_f(float* p) { return atomicAdd(p, 0.0f); }
__device__ __forceinline__ int   aread_i(int* p)   { return atomicAdd(p, 0); }

__device__ void final_combine(float* wsf, int c0, int c1,
                              const float* sdet, const float* sid,
                              float* out) {
    int* wsi = (int*)wsf;
    (void)wsi;
    float pos  = aread_f(wsf + 0), neg = aread_f(wsf + 1), npos = aread_f(wsf + 2);
    float swh  = aread_f(wsf + 3), soff = aread_f(wsf + 4), msum = aread_f(wsf + 5);
    float nll0 = aread_f(wsf + 6), nll1 = aread_f(wsf + 7);
    float hm_loss = (npos > 0.f) ? -(pos + neg) / fmaxf(npos, 1.f) : -neg;
    float wh_loss  = swh  / (msum * 2.f + 1e-4f);
    float off_loss = soff / (msum * 2.f + 1e-4f);
    float reid = 0.f;
    if (c0 > 0) {
        float nv = (float)(c0 < KG ? c0 : KG);
        reid += (nll0 / fmaxf(nv, 1.f)) / fmaxf((float)c0, 1.f);
    }
    if (c1 > 0) {
        float nv = (float)(c1 < KG ? c1 : KG);
        reid += (nll1 / fmaxf(nv, 1.f)) / fmaxf((float)c1, 1.f);
    }
    float det = hm_loss + 0.1f * wh_loss + off_loss;
    float sd = sdet[0], si = sid[0];
    out[0] = 0.5f * (__expf(-sd) * det + __expf(-si) * reid + sd + si);
    out[1] = hm_loss;
    out[2] = wh_loss;
    out[3] = off_loss;
    out[4] = reid;
}

__global__ __launch_bounds__(256, 2)
void mega_kernel(const float4* __restrict__ hp, const float4* __restrict__ gt,
                 const int4* __restrict__ cmap,
                 const float* __restrict__ wh_pred, const float* __restrict__ reg_pred,
                 const float* __restrict__ wh, const float* __restrict__ reg,
                 const float* __restrict__ mask, const int* __restrict__ ind,
                 const float* __restrict__ id_pred, const int* __restrict__ cls_tr,
                 const float* __restrict__ W0, const float* __restrict__ b0,
                 const float* __restrict__ W1, const float* __restrict__ b1,
                 const float* __restrict__ sdet, const float* __restrict__ sid,
                 float* __restrict__ wsf, float* __restrict__ out,
                 float esc0, float esc1, int n4, int nc4)
{
    int* wsi = (int*)wsf;
    int tid = threadIdx.x;
    int gid = blockIdx.x * 256 + tid;
    const int gstride = GRID * 256;

    __shared__ int stage0[1024], stage1[1024];
    __shared__ int lcnt0, lcnt1, gbase0, gbase1;
    __shared__ float sm[3][4];
    // phase-B shared (disjoint usage after barrier; keep separate for simplicity)
    __shared__ float emb_s[TE][EMBD];
    __shared__ int   tgt_s[TE];
    __shared__ float tgtl_s[TE];
    __shared__ float red_m[TE][4];
    __shared__ float red_s[TE][4];

    if (tid == 0) { lcnt0 = 0; lcnt1 = 0; }
    __syncthreads();

    // ---------- Phase A1: compaction of cls_id_map (LDS staging) ----------
    for (int i = gid; i < nc4; i += gstride) {
        int4 v = cmap[i];
        int b4 = i * 4;
        if (v.x == 0) stage0[atomicAdd(&lcnt0,1)] = b4+0; else if (v.x == 1) stage1[atomicAdd(&lcnt1,1)] = b4+0;
        if (v.y == 0) stage0[atomicAdd(&lcnt0,1)] = b4+1; else if (v.y == 1) stage1[atomicAdd(&lcnt1,1)] = b4+1;
        if (v.z == 0) stage0[atomicAdd(&lcnt0,1)] = b4+2; else if (v.z == 1) stage1[atomicAdd(&lcnt1,1)] = b4+2;
        if (v.w == 0) stage0[atomicAdd(&lcnt0,1)] = b4+3; else if (v.w == 1) stage1[atomicAdd(&lcnt1,1)] = b4+3;
    }
    __syncthreads();
    if (tid == 0) gbase0 = (lcnt0 > 0) ? atomicAdd(wsi + 8, lcnt0) : 0;
    if (tid == 1) gbase1 = (lcnt1 > 0) ? atomicAdd(wsi + 9, lcnt1) : 0;
    __syncthreads();
    for (int j = tid; j < lcnt0; j += 256) { int q = gbase0 + j; if (q < KG) wsi[16 + q] = stage0[j]; }
    for (int j = tid; j < lcnt1; j += 256) { int q = gbase1 + j; if (q < KG) wsi[16 + KG + q] = stage1[j]; }

    // ---------- Phase A2: focal loss ----------
    {
        float pos = 0.f, neg = 0.f, cnt = 0.f;
        for (int i = gid; i < n4; i += gstride) {
            float4 x = hp[i];
            float4 g = gt[i];
            float xs[4] = {x.x, x.y, x.z, x.w};
            float gs[4] = {g.x, g.y, g.z, g.w};
            #pragma unroll
            for (int j = 0; j < 4; ++j) {
                float s = 1.f / (1.f + __expf(-xs[j]));
                s = fminf(fmaxf(s, 1e-4f), 1.f - 1e-4f);
                float gv = gs[j];
                if (gv == 1.f) {
                    float om = 1.f - s;
                    pos += __logf(s) * om * om;
                    cnt += 1.f;
                } else {
                    float nw = 1.f - gv; nw = nw * nw; nw = nw * nw;
                    neg += __logf(1.f - s) * s * s * nw;
                }
            }
        }
        float a = wave_sum(pos), b = wave_sum(neg), c = wave_sum(cnt);
        int lane = tid & 63, wid = tid >> 6;
        if (lane == 0) { sm[0][wid] = a; sm[1][wid] = b; sm[2][wid] = c; }
        __syncthreads();
        if (tid == 0) {
            float s0 = 0, s1 = 0, s2 = 0;
            #pragma unroll
            for (int w = 0; w < 4; ++w) { s0 += sm[0][w]; s1 += sm[1][w]; s2 += sm[2][w]; }
            atomicAdd(wsf + 0, s0);
            atomicAdd(wsf + 1, s1);
            atomicAdd(wsf + 2, s2);
        }
    }

    // ---------- Phase A3: wh / off L1 (block 0) ----------
    if (blockIdx.x == 0) {
        __syncthreads();
        float nwh = 0.f, noff = 0.f, msum = 0.f;
        for (int t = tid; t < BB * KOBJ; t += 256) {
            int b = t / KOBJ;
            float m = mask[t];
            int id = ind[t];
            const float* wp = wh_pred + (size_t)b * 2 * HW;
            const float* rp = reg_pred + (size_t)b * 2 * HW;
            float p0 = wp[id], p1 = wp[HW + id];
            float q0 = rp[id], q1 = rp[HW + id];
            float t0 = wh[t * 2], t1 = wh[t * 2 + 1];
            float r0 = reg[t * 2], r1 = reg[t * 2 + 1];
            nwh  += fabsf(p0 * m - t0 * m) + fabsf(p1 * m - t1 * m);
            noff += fabsf(q0 * m - r0 * m) + fabsf(q1 * m - r1 * m);
            msum += m;
        }
        float a = wave_sum(nwh), b = wave_sum(noff), c = wave_sum(msum);
        int lane = tid & 63, wid = tid >> 6;
        if (lane == 0) { sm[0][wid] = a; sm[1][wid] = b; sm[2][wid] = c; }
        __syncthreads();
        if (tid == 0) {
            float s0 = 0, s1 = 0, s2 = 0;
            #pragma unroll
            for (int w = 0; w < 4; ++w) { s0 += sm[0][w]; s1 += sm[1][w]; s2 += sm[2][w]; }
            atomicAdd(wsf + 3, s0);
            atomicAdd(wsf + 4, s1);
            atomicAdd(wsf + 5, s2);
        }
    }

    // ---------- Grid barrier (all 512 blocks co-resident by launch_bounds) ----------
    __threadfence();
    __syncthreads();
    if (tid == 0) {
        atomicAdd(wsi + 11, 1);
        while (aread_i(wsi + 11) < GRID) __builtin_amdgcn_s_sleep(8);
    }
    __syncthreads();

    // ---------- Phase B: reid tiles (gather into LDS + logits + lse) ----------
    int c0full = aread_i(wsi + 8);
    int c1full = aread_i(wsi + 9);
    int m0 = c0full < KG ? c0full : KG;
    int m1 = c1full < KG ? c1full : KG;
    int a0 = (m0 + TE - 1) / TE, a1 = (m1 + TE - 1) / TE;
    int nact = a0 + a1;

    if (nact == 0) {
        if (blockIdx.x == 0 && tid == 0)
            final_combine(wsf, c0full, c1full, sdet, sid, out);
        return;
    }
    int t = blockIdx.x;
    if (t >= nact) return;
    int cls  = (t < a0) ? 0 : 1;
    int tile = (t < a0) ? t : t - a0;
    int m    = cls ? m1 : m0;
    int base = tile * TE;
    int nval = m - base; if (nval > TE) nval = TE;

    int nid = cls ? NID1 : NID0;
    const float* Wc = cls ? W1 : W0;
    const float* bc = cls ? b1 : b0;
    int* idxArr = wsi + 16 + cls * KG;
    float escale = cls ? esc1 : esc0;

    // gather: 16 threads per entry, 8 channels each; normalize; stage in LDS
    {
        int e  = tid >> 4;          // entry within tile
        int cg = tid & 15;          // channel group
        if (e < nval) {
            int p = aread_i(idxArr + base + e);       // device-coherent read
            int b = p / HW, hw = p - b * HW;
            const float* src = id_pred + (size_t)b * EMBD * HW + hw;
            float f[8];
            float ss = 0.f;
            #pragma unroll
            for (int j = 0; j < 8; ++j) {
                f[j] = src[(size_t)(cg * 8 + j) * HW];
                ss += f[j] * f[j];
            }
            #pragma unroll
            for (int o = 1; o < 16; o <<= 1) ss += __shfl_xor(ss, o, 64);
            float scale = escale / fmaxf(__builtin_sqrtf(ss), 1e-12f);
            float4* dst = (float4*)&emb_s[e][cg * 8];
            dst[0] = make_float4(f[0]*scale, f[1]*scale, f[2]*scale, f[3]*scale);
            dst[1] = make_float4(f[4]*scale, f[5]*scale, f[6]*scale, f[7]*scale);
        } else {
            float4* dst = (float4*)&emb_s[e][cg * 8];
            dst[0] = make_float4(0.f, 0.f, 0.f, 0.f);
            dst[1] = make_float4(0.f, 0.f, 0.f, 0.f);
        }
        if (tid < TE) {
            int tg = -1;
            if (tid < nval) {
                int p = aread_i(idxArr + base + tid);
                int b = p / HW, hw = p - b * HW;
                tg = cls_tr[((size_t)b * 2 + cls) * HW + hw];
            }
            tgt_s[tid] = tg;
            tgtl_s[tid] = 0.f;
        }
    }
    __syncthreads();

    // logits: rows r0 = tid, r1 = tid + 256
    int r0 = tid, r1 = tid + 256;
    bool v1ok = r1 < nid;
    const float4* wr0 = (const float4*)(Wc + (size_t)r0 * EMBD);
    const float4* wr1 = (const float4*)(Wc + (size_t)(v1ok ? r1 : 0) * EMBD);

    float acc0[TE], acc1[TE];
    #pragma unroll
    for (int e = 0; e < TE; ++e) { acc0[e] = 0.f; acc1[e] = 0.f; }

    for (int j = 0; j < EMBD / 4; ++j) {
        float4 w0 = wr0[j];
        float4 w1 = wr1[j];
        #pragma unroll
        for (int e = 0; e < TE; ++e) {
            float4 em = ((const float4*)emb_s[e])[j];   // wave-broadcast LDS read
            acc0[e] = fmaf(w0.x, em.x, fmaf(w0.y, em.y, fmaf(w0.z, em.z, fmaf(w0.w, em.w, acc0[e]))));
            acc1[e] = fmaf(w1.x, em.x, fmaf(w1.y, em.y, fmaf(w1.z, em.z, fmaf(w1.w, em.w, acc1[e]))));
        }
    }
    float bias0 = bc[r0];
    float bias1 = v1ok ? bc[r1] : 0.f;
    #pragma unroll
    for (int e = 0; e < TE; ++e) {
        acc0[e] += bias0;
        acc1[e] = v1ok ? (acc1[e] + bias1) : -1e30f;
        if (r0 == tgt_s[e]) tgtl_s[e] = acc0[e];
        if (v1ok && r1 == tgt_s[e]) tgtl_s[e] = acc1[e];
    }

    int lane = tid & 63, wid = tid >> 6;

    // pass 1: block max per entry
    float mx[TE];
    #pragma unroll
    for (int e = 0; e < TE; ++e) mx[e] = fmaxf(acc0[e], acc1[e]);
    #pragma unroll
    for (int o = 32; o > 0; o >>= 1) {
        #pragma unroll
        for (int e = 0; e < TE; ++e) mx[e] = fmaxf(mx[e], __shfl_xor(mx[e], o, 64));
    }
    if (lane == 0) {
        #pragma unroll
        for (int e = 0; e < TE; ++e) red_m[e][wid] = mx[e];
    }
    __syncthreads();
    float bm[TE];
    #pragma unroll
    for (int e = 0; e < TE; ++e)
        bm[e] = fmaxf(fmaxf(red_m[e][0], red_m[e][1]), fmaxf(red_m[e][2], red_m[e][3]));

    // pass 2: sum of exps
    float se[TE];
    #pragma unroll
    for (int e = 0; e < TE; ++e) se[e] = __expf(acc0[e] - bm[e]) + __expf(acc1[e] - bm[e]);
    #pragma unroll
    for (int o = 32; o > 0; o >>= 1) {
        #pragma unroll
        for (int e = 0; e < TE; ++e) se[e] += __shfl_xor(se[e], o, 64);
    }
    if (lane == 0) {
        #pragma unroll
        for (int e = 0; e < TE; ++e) red_s[e][wid] = se[e];
    }
    __syncthreads();

    if (tid == 0) {
        float nll = 0.f;
        #pragma unroll
        for (int e = 0; e < TE; ++e) {
            if (e < nval) {
                float S = red_s[e][0] + red_s[e][1] + red_s[e][2] + red_s[e][3];
                nll += bm[e] + __logf(S) - tgtl_s[e];
            }
        }
        atomicAdd(wsf + 6 + cls, nll);
        __threadfence();
        int old = atomicAdd(wsi + 10, 1);
        if (old == nact - 1)
            final_combine(wsf, c0full, c1full, sdet, sid, out);
    }
}

extern "C" void kernel_launch(void* const* d_in, const int* in_sizes, int n_in,
                              void* d_out, int out_size, void* d_ws, size_t ws_size,
                              hipStream_t stream) {
    const float* hm_pred   = (const float*)d_in[0];
    const float* wh_pred   = (const float*)d_in[1];
    const float* reg_pred  = (const float*)d_in[2];
    const float* id_pred   = (const float*)d_in[3];
    const float* hm        = (const float*)d_in[4];
    const float* wh        = (const float*)d_in[5];
    const float* reg       = (const float*)d_in[6];
    const float* reg_mask  = (const float*)d_in[7];
    const int*   ind       = (const int*)d_in[8];
    const int*   cls_map   = (const int*)d_in[9];
    const int*   cls_tr    = (const int*)d_in[10];
    const float* W0        = (const float*)d_in[11];
    const float* b0        = (const float*)d_in[12];
    const float* W1        = (const float*)d_in[13];
    const float* b1        = (const float*)d_in[14];
    const float* s_det     = (const float*)d_in[15];
    const float* s_id      = (const float*)d_in[16];

    float* wsf = (float*)d_ws;

    // zero the 16-word accumulator/barrier header each call
    hipMemsetAsync(d_ws, 0, 64, stream);

    const int n4  = (BB * HMC * HW) / 4;   // 165376
    const int nc4 = (BB * HW) / 4;         // 82688
    const float esc0 = (float)(sqrt(2.0) * log((double)NID0 - 1.0));
    const float esc1 = (float)(sqrt(2.0) * log((double)NID1 - 1.0));

    mega_kernel<<<GRID, 256, 0, stream>>>(
        (const float4*)hm_pred, (const float4*)hm, (const int4*)cls_map,
        wh_pred, reg_pred, wh, reg, reg_mask, ind,
        id_pred, cls_tr, W0, b0, W1, b1, s_det, s_id,
        wsf, (float*)d_out, esc0, esc1, n4, nc4);
}

// Round 5
// 126.805 us; speedup vs baseline: 1.0255x; 1.0255x over previous
//
#include <hip/hip_runtime.h>
#include <math.h>

// Problem constants (from reference)
#define BB    8
#define HMC   2
#define HW    41344           // 152*272
#define EMBD  128
#define KOBJ  128
#define KG    8192
#define NID0  500
#define NID1  300
#define TE    16              // entries per logits tile
#define GRID  512             // co-resident: launch_bounds(256,2) -> 2 blocks/CU x 256 CU

// d_ws layout (words):
//   [0] pos_loss [1] neg_loss [2] num_pos [3] num_wh [4] num_off [5] mask_sum
//   [6] nll0 [7] nll1  (float accumulators)
//   [8] cnt0 [9] cnt1  (int)  [10] done-counter  [11] barrier counter
//   [16 .. 16+KG)  idx0    [16+KG .. 16+2KG)  idx1
// (memset node zeroes words 0..15 each replay)

__device__ __forceinline__ float wave_sum(float v) {
    #pragma unroll
    for (int o = 32; o > 0; o >>= 1) v += __shfl_down(v, o, 64);
    return v;
}
// Agent(device)-scope loads: served at the coherence point, NO RMW ownership
// ping-pong (the R4 barrier bug: atomicAdd(p,0) polling serialized ~150cyc/RMW).
__device__ __forceinline__ int ld_i_acq(int* p) {
    return __hip_atomic_load(p, __ATOMIC_ACQUIRE, __HIP_MEMORY_SCOPE_AGENT);
}
__device__ __forceinline__ int ld_i_rlx(int* p) {
    return __hip_atomic_load(p, __ATOMIC_RELAXED, __HIP_MEMORY_SCOPE_AGENT);
}
__device__ __forceinline__ float ld_f_rlx(float* p) {
    return __hip_atomic_load(p, __ATOMIC_RELAXED, __HIP_MEMORY_SCOPE_AGENT);
}

__device__ void final_combine(float* wsf, int c0, int c1,
                              const float* sdet, const float* sid,
                              float* out) {
    float pos  = ld_f_rlx(wsf + 0), neg = ld_f_rlx(wsf + 1), npos = ld_f_rlx(wsf + 2);
    float swh  = ld_f_rlx(wsf + 3), soff = ld_f_rlx(wsf + 4), msum = ld_f_rlx(wsf + 5);
    float nll0 = ld_f_rlx(wsf + 6), nll1 = ld_f_rlx(wsf + 7);
    float hm_loss = (npos > 0.f) ? -(pos + neg) / fmaxf(npos, 1.f) : -neg;
    float wh_loss  = swh  / (msum * 2.f + 1e-4f);
    float off_loss = soff / (msum * 2.f + 1e-4f);
    float reid = 0.f;
    if (c0 > 0) {
        float nv = (float)(c0 < KG ? c0 : KG);
        reid += (nll0 / fmaxf(nv, 1.f)) / fmaxf((float)c0, 1.f);
    }
    if (c1 > 0) {
        float nv = (float)(c1 < KG ? c1 : KG);
        reid += (nll1 / fmaxf(nv, 1.f)) / fmaxf((float)c1, 1.f);
    }
    float det = hm_loss + 0.1f * wh_loss + off_loss;
    float sd = sdet[0], si = sid[0];
    out[0] = 0.5f * (__expf(-sd) * det + __expf(-si) * reid + sd + si);
    out[1] = hm_loss;
    out[2] = wh_loss;
    out[3] = off_loss;
    out[4] = reid;
}

__global__ __launch_bounds__(256, 2)
void mega_kernel(const float4* __restrict__ hp, const float4* __restrict__ gt,
                 const int4* __restrict__ cmap,
                 const float* __restrict__ wh_pred, const float* __restrict__ reg_pred,
                 const float* __restrict__ wh, const float* __restrict__ reg,
                 const float* __restrict__ mask, const int* __restrict__ ind,
                 const float* __restrict__ id_pred, const int* __restrict__ cls_tr,
                 const float* __restrict__ W0, const float* __restrict__ b0,
                 const float* __restrict__ W1, const float* __restrict__ b1,
                 const float* __restrict__ sdet, const float* __restrict__ sid,
                 float* __restrict__ wsf, float* __restrict__ out,
                 float esc0, float esc1, int n4, int nc4)
{
    int* wsi = (int*)wsf;
    int tid = threadIdx.x;
    const int gstride = GRID * 256;

    __shared__ int stage0[1024], stage1[1024];
    __shared__ int lcnt0, lcnt1, gbase0, gbase1;
    __shared__ float sm[3][4];
    __shared__ float emb_s[TE][EMBD];
    __shared__ int   tgt_s[TE];
    __shared__ float tgtl_s[TE];
    __shared__ float red_m[TE][4];
    __shared__ float red_s[TE][4];

    if (tid == 0) { lcnt0 = 0; lcnt1 = 0; }
    __syncthreads();

    // ---------- Phase A: compaction of cls_id_map (LDS staging) ----------
    for (int i = blockIdx.x * 256 + tid; i < nc4; i += gstride) {
        int4 v = cmap[i];
        int b4 = i * 4;
        if (v.x == 0) stage0[atomicAdd(&lcnt0,1)] = b4+0; else if (v.x == 1) stage1[atomicAdd(&lcnt1,1)] = b4+0;
        if (v.y == 0) stage0[atomicAdd(&lcnt0,1)] = b4+1; else if (v.y == 1) stage1[atomicAdd(&lcnt1,1)] = b4+1;
        if (v.z == 0) stage0[atomicAdd(&lcnt0,1)] = b4+2; else if (v.z == 1) stage1[atomicAdd(&lcnt1,1)] = b4+2;
        if (v.w == 0) stage0[atomicAdd(&lcnt0,1)] = b4+3; else if (v.w == 1) stage1[atomicAdd(&lcnt1,1)] = b4+3;
    }
    __syncthreads();
    if (tid == 0) gbase0 = (lcnt0 > 0) ? atomicAdd(wsi + 8, lcnt0) : 0;
    if (tid == 1) gbase1 = (lcnt1 > 0) ? atomicAdd(wsi + 9, lcnt1) : 0;
    __syncthreads();
    for (int j = tid; j < lcnt0; j += 256) { int q = gbase0 + j; if (q < KG) wsi[16 + q] = stage0[j]; }
    for (int j = tid; j < lcnt1; j += 256) { int q = gbase1 + j; if (q < KG) wsi[16 + KG + q] = stage1[j]; }

    // ---------- Grid barrier (load-polling, agent scope) ----------
    __threadfence();
    __syncthreads();
    if (tid == 0) {
        __hip_atomic_fetch_add(wsi + 11, 1, __ATOMIC_ACQ_REL, __HIP_MEMORY_SCOPE_AGENT);
        while (ld_i_acq(wsi + 11) < GRID) __builtin_amdgcn_s_sleep(32);
    }
    __syncthreads();

    // ---------- Phase B work split ----------
    int c0full = ld_i_rlx(wsi + 8);
    int c1full = ld_i_rlx(wsi + 9);
    int m0 = c0full < KG ? c0full : KG;
    int m1 = c1full < KG ? c1full : KG;
    int a0 = (m0 + TE - 1) / TE, a1 = (m1 + TE - 1) / TE;
    int nact = a0 + a1;
    int rblk = nact < 256 ? nact : 256;   // blocks [0,rblk) = reid; rest = focal/reg

    if (blockIdx.x < rblk) {
        // ===== reid tiles (tile-strided) =====
        for (int t = blockIdx.x; t < nact; t += rblk) {
            int cls  = (t < a0) ? 0 : 1;
            int tile = (t < a0) ? t : t - a0;
            int m    = cls ? m1 : m0;
            int base = tile * TE;
            int nval = m - base; if (nval > TE) nval = TE;

            int nid = cls ? NID1 : NID0;
            const float* Wc = cls ? W1 : W0;
            const float* bc = cls ? b1 : b0;
            int* idxArr = wsi + 16 + cls * KG;
            float escale = cls ? esc1 : esc0;

            // gather: 16 threads per entry, 8 channels each
            {
                int e  = tid >> 4;
                int cg = tid & 15;
                if (e < nval) {
                    int p = ld_i_rlx(idxArr + base + e);
                    int b = p / HW, hw = p - b * HW;
                    const float* src = id_pred + (size_t)b * EMBD * HW + hw;
                    float f[8];
                    float ss = 0.f;
                    #pragma unroll
                    for (int j = 0; j < 8; ++j) {
                        f[j] = src[(size_t)(cg * 8 + j) * HW];
                        ss += f[j] * f[j];
                    }
                    #pragma unroll
                    for (int o = 1; o < 16; o <<= 1) ss += __shfl_xor(ss, o, 64);
                    float scale = escale / fmaxf(__builtin_sqrtf(ss), 1e-12f);
                    float4* dst = (float4*)&emb_s[e][cg * 8];
                    dst[0] = make_float4(f[0]*scale, f[1]*scale, f[2]*scale, f[3]*scale);
                    dst[1] = make_float4(f[4]*scale, f[5]*scale, f[6]*scale, f[7]*scale);
                } else {
                    float4* dst = (float4*)&emb_s[e][cg * 8];
                    dst[0] = make_float4(0.f, 0.f, 0.f, 0.f);
                    dst[1] = make_float4(0.f, 0.f, 0.f, 0.f);
                }
                if (tid < TE) {
                    int tg = -1;
                    if (tid < nval) {
                        int p = ld_i_rlx(idxArr + base + tid);
                        int b = p / HW, hw = p - b * HW;
                        tg = cls_tr[((size_t)b * 2 + cls) * HW + hw];
                    }
                    tgt_s[tid] = tg;
                    tgtl_s[tid] = 0.f;
                }
            }
            __syncthreads();

            // logits rows r0 = tid, r1 = tid + 256
            int r0 = tid, r1 = tid + 256;
            bool v1ok = r1 < nid;
            const float4* wr0 = (const float4*)(Wc + (size_t)r0 * EMBD);
            const float4* wr1 = (const float4*)(Wc + (size_t)(v1ok ? r1 : 0) * EMBD);

            float acc0[TE], acc1[TE];
            #pragma unroll
            for (int e = 0; e < TE; ++e) { acc0[e] = 0.f; acc1[e] = 0.f; }

            for (int j = 0; j < EMBD / 4; ++j) {
                float4 w0 = wr0[j];
                float4 w1 = wr1[j];
                #pragma unroll
                for (int e = 0; e < TE; ++e) {
                    float4 em = ((const float4*)emb_s[e])[j];
                    acc0[e] = fmaf(w0.x, em.x, fmaf(w0.y, em.y, fmaf(w0.z, em.z, fmaf(w0.w, em.w, acc0[e]))));
                    acc1[e] = fmaf(w1.x, em.x, fmaf(w1.y, em.y, fmaf(w1.z, em.z, fmaf(w1.w, em.w, acc1[e]))));
                }
            }
            float bias0 = bc[r0];
            float bias1 = v1ok ? bc[r1] : 0.f;
            #pragma unroll
            for (int e = 0; e < TE; ++e) {
                acc0[e] += bias0;
                acc1[e] = v1ok ? (acc1[e] + bias1) : -1e30f;
                if (r0 == tgt_s[e]) tgtl_s[e] = acc0[e];
                if (v1ok && r1 == tgt_s[e]) tgtl_s[e] = acc1[e];
            }

            int lane = tid & 63, wid = tid >> 6;

            float mx[TE];
            #pragma unroll
            for (int e = 0; e < TE; ++e) mx[e] = fmaxf(acc0[e], acc1[e]);
            #pragma unroll
            for (int o = 32; o > 0; o >>= 1) {
                #pragma unroll
                for (int e = 0; e < TE; ++e) mx[e] = fmaxf(mx[e], __shfl_xor(mx[e], o, 64));
            }
            if (lane == 0) {
                #pragma unroll
                for (int e = 0; e < TE; ++e) red_m[e][wid] = mx[e];
            }
            __syncthreads();
            float bm[TE];
            #pragma unroll
            for (int e = 0; e < TE; ++e)
                bm[e] = fmaxf(fmaxf(red_m[e][0], red_m[e][1]), fmaxf(red_m[e][2], red_m[e][3]));

            float se[TE];
            #pragma unroll
            for (int e = 0; e < TE; ++e) se[e] = __expf(acc0[e] - bm[e]) + __expf(acc1[e] - bm[e]);
            #pragma unroll
            for (int o = 32; o > 0; o >>= 1) {
                #pragma unroll
                for (int e = 0; e < TE; ++e) se[e] += __shfl_xor(se[e], o, 64);
            }
            if (lane == 0) {
                #pragma unroll
                for (int e = 0; e < TE; ++e) red_s[e][wid] = se[e];
            }
            __syncthreads();

            if (tid == 0) {
                float nll = 0.f;
                #pragma unroll
                for (int e = 0; e < TE; ++e) {
                    if (e < nval) {
                        float S = red_s[e][0] + red_s[e][1] + red_s[e][2] + red_s[e][3];
                        nll += bm[e] + __logf(S) - tgtl_s[e];
                    }
                }
                atomicAdd(wsf + 6 + cls, nll);
            }
            __syncthreads();   // protect shared reuse across tile iterations
        }
    } else {
        // ===== focal loss on blocks [rblk, GRID) =====
        int fb = blockIdx.x - rblk;
        int fstride = (GRID - rblk) * 256;
        float pos = 0.f, neg = 0.f, cnt = 0.f;
        for (int i = fb * 256 + tid; i < n4; i += fstride) {
            float4 x = hp[i];
            float4 g = gt[i];
            float xs[4] = {x.x, x.y, x.z, x.w};
            float gs[4] = {g.x, g.y, g.z, g.w};
            #pragma unroll
            for (int j = 0; j < 4; ++j) {
                float s = 1.f / (1.f + __expf(-xs[j]));
                s = fminf(fmaxf(s, 1e-4f), 1.f - 1e-4f);
                float gv = gs[j];
                if (gv == 1.f) {
                    float om = 1.f - s;
                    pos += __logf(s) * om * om;
                    cnt += 1.f;
                } else {
                    float nw = 1.f - gv; nw = nw * nw; nw = nw * nw;
                    neg += __logf(1.f - s) * s * s * nw;
                }
            }
        }
        {
            float a = wave_sum(pos), b = wave_sum(neg), c = wave_sum(cnt);
            int lane = tid & 63, wid = tid >> 6;
            if (lane == 0) { sm[0][wid] = a; sm[1][wid] = b; sm[2][wid] = c; }
            __syncthreads();
            if (tid == 0) {
                float s0 = 0, s1 = 0, s2 = 0;
                #pragma unroll
                for (int w = 0; w < 4; ++w) { s0 += sm[0][w]; s1 += sm[1][w]; s2 += sm[2][w]; }
                atomicAdd(wsf + 0, s0);
                atomicAdd(wsf + 1, s1);
                atomicAdd(wsf + 2, s2);
            }
        }

        // reg (wh/off) on the last block
        if (blockIdx.x == GRID - 1) {
            __syncthreads();
            float nwh = 0.f, noff = 0.f, msum = 0.f;
            for (int t = tid; t < BB * KOBJ; t += 256) {
                int b = t / KOBJ;
                float m = mask[t];
                int id = ind[t];
                const float* wp = wh_pred + (size_t)b * 2 * HW;
                const float* rp = reg_pred + (size_t)b * 2 * HW;
                float p0 = wp[id], p1 = wp[HW + id];
                float q0 = rp[id], q1 = rp[HW + id];
                float t0 = wh[t * 2], t1 = wh[t * 2 + 1];
                float r0 = reg[t * 2], r1 = reg[t * 2 + 1];
                nwh  += fabsf(p0 * m - t0 * m) + fabsf(p1 * m - t1 * m);
                noff += fabsf(q0 * m - r0 * m) + fabsf(q1 * m - r1 * m);
                msum += m;
            }
            float a = wave_sum(nwh), b = wave_sum(noff), c = wave_sum(msum);
            int lane = tid & 63, wid = tid >> 6;
            if (lane == 0) { sm[0][wid] = a; sm[1][wid] = b; sm[2][wid] = c; }
            __syncthreads();
            if (tid == 0) {
                float s0 = 0, s1 = 0, s2 = 0;
                #pragma unroll
                for (int w = 0; w < 4; ++w) { s0 += sm[0][w]; s1 += sm[1][w]; s2 += sm[2][w]; }
                atomicAdd(wsf + 3, s0);
                atomicAdd(wsf + 4, s1);
                atomicAdd(wsf + 5, s2);
            }
        }
    }

    // ---------- done-counter: last of all 512 blocks runs final combine ----------
    __syncthreads();
    if (tid == 0) {
        __threadfence();
        int old = __hip_atomic_fetch_add(wsi + 10, 1, __ATOMIC_ACQ_REL, __HIP_MEMORY_SCOPE_AGENT);
        if (old == GRID - 1)
            final_combine(wsf, c0full, c1full, sdet, sid, out);
    }
}

extern "C" void kernel_launch(void* const* d_in, const int* in_sizes, int n_in,
                              void* d_out, int out_size, void* d_ws, size_t ws_size,
                              hipStream_t stream) {
    const float* hm_pred   = (const float*)d_in[0];
    const float* wh_pred   = (const float*)d_in[1];
    const float* reg_pred  = (const float*)d_in[2];
    const float* id_pred   = (const float*)d_in[3];
    const float* hm        = (const float*)d_in[4];
    const float* wh        = (const float*)d_in[5];
    const float* reg       = (const float*)d_in[6];
    const float* reg_mask  = (const float*)d_in[7];
    const int*   ind       = (const int*)d_in[8];
    const int*   cls_map   = (const int*)d_in[9];
    const int*   cls_tr    = (const int*)d_in[10];
    const float* W0        = (const float*)d_in[11];
    const float* b0        = (const float*)d_in[12];
    const float* W1        = (const float*)d_in[13];
    const float* b1        = (const float*)d_in[14];
    const float* s_det     = (const float*)d_in[15];
    const float* s_id      = (const float*)d_in[16];

    float* wsf = (float*)d_ws;

    // zero the 16-word accumulator/barrier header each call
    hipMemsetAsync(d_ws, 0, 64, stream);

    const int n4  = (BB * HMC * HW) / 4;   // 165376
    const int nc4 = (BB * HW) / 4;         // 82688
    const float esc0 = (float)(sqrt(2.0) * log((double)NID0 - 1.0));
    const float esc1 = (float)(sqrt(2.0) * log((double)NID1 - 1.0));

    mega_kernel<<<GRID, 256, 0, stream>>>(
        (const float4*)hm_pred, (const float4*)hm, (const int4*)cls_map,
        wh_pred, reg_pred, wh, reg, reg_mask, ind,
        id_pred, cls_tr, W0, b0, W1, b1, s_det, s_id,
        wsf, (float*)d_out, esc0, esc1, n4, nc4);
}

// Round 6
// 89.648 us; speedup vs baseline: 1.4506x; 1.4145x over previous
//
#include <hip/hip_runtime.h>
#include <math.h>

// Problem constants (from reference)
#define BB    8
#define HMC   2
#define HW    41344           // 152*272
#define EMBD  128
#define KOBJ  128
#define KG    8192
#define NID0  500
#define NID1  300
#define TE    8               // entries per logits tile (local matches per pass)
#define GRID  256
#define CH4   323             // int4 per block chunk: 256*323 == 82688 == (B*HW)/4 exactly
#define MAXM  96              // per-block per-class match cap (binomial mean ~6.5, P(>96)~0)

// d_ws layout (words):
//   [0] pos_loss [1] neg_loss [2] num_pos [3] num_wh [4] num_off [5] mask_sum
//   [6] nll0 [7] nll1  (float accumulators)
//   [8] cnt0 [9] cnt1  (int)  [10] done-counter
// (memset node zeroes words 0..15 each replay)

__device__ __forceinline__ float wave_sum(float v) {
    #pragma unroll
    for (int o = 32; o > 0; o >>= 1) v += __shfl_down(v, o, 64);
    return v;
}
__device__ __forceinline__ int ld_i(int* p) {
    return __hip_atomic_load(p, __ATOMIC_RELAXED, __HIP_MEMORY_SCOPE_AGENT);
}
__device__ __forceinline__ float ld_f(float* p) {
    return __hip_atomic_load(p, __ATOMIC_RELAXED, __HIP_MEMORY_SCOPE_AGENT);
}

__device__ void final_combine(float* wsf, const float* sdet, const float* sid,
                              float* out) {
    int* wsi = (int*)wsf;
    float pos  = ld_f(wsf + 0), neg = ld_f(wsf + 1), npos = ld_f(wsf + 2);
    float swh  = ld_f(wsf + 3), soff = ld_f(wsf + 4), msum = ld_f(wsf + 5);
    float nll0 = ld_f(wsf + 6), nll1 = ld_f(wsf + 7);
    int c0 = ld_i(wsi + 8), c1 = ld_i(wsi + 9);
    float hm_loss = (npos > 0.f) ? -(pos + neg) / fmaxf(npos, 1.f) : -neg;
    float wh_loss  = swh  / (msum * 2.f + 1e-4f);
    float off_loss = soff / (msum * 2.f + 1e-4f);
    float reid = 0.f;
    if (c0 > 0) {
        float nv = (float)(c0 < KG ? c0 : KG);
        reid += (nll0 / fmaxf(nv, 1.f)) / fmaxf((float)c0, 1.f);
    }
    if (c1 > 0) {
        float nv = (float)(c1 < KG ? c1 : KG);
        reid += (nll1 / fmaxf(nv, 1.f)) / fmaxf((float)c1, 1.f);
    }
    float det = hm_loss + 0.1f * wh_loss + off_loss;
    float sd = sdet[0], si = sid[0];
    out[0] = 0.5f * (__expf(-sd) * det + __expf(-si) * reid + sd + si);
    out[1] = hm_loss;
    out[2] = wh_loss;
    out[3] = off_loss;
    out[4] = reid;
}

__global__ __launch_bounds__(256)
void mega_kernel(const float4* __restrict__ hp, const float4* __restrict__ gt,
                 const int4* __restrict__ cmap,
                 const float* __restrict__ wh_pred, const float* __restrict__ reg_pred,
                 const float* __restrict__ wh, const float* __restrict__ reg,
                 const float* __restrict__ mask, const int* __restrict__ ind,
                 const float* __restrict__ id_pred, const int* __restrict__ cls_tr,
                 const float* __restrict__ W0, const float* __restrict__ b0,
                 const float* __restrict__ W1, const float* __restrict__ b1,
                 const float* __restrict__ sdet, const float* __restrict__ sid,
                 float* __restrict__ wsf, float* __restrict__ out,
                 float esc0, float esc1, int n4)
{
    int* wsi = (int*)wsf;
    int tid = threadIdx.x;
    int bid = blockIdx.x;

    __shared__ int   pos_s[2][MAXM];
    __shared__ int   lc_s[2];
    __shared__ float sm[3][4];
    __shared__ float emb_s[TE][EMBD];
    __shared__ int   tgt_s[TE];
    __shared__ float tgtl_s[TE];
    __shared__ float red_m[TE][4];
    __shared__ float red_s[TE][4];

    if (tid < 2) lc_s[tid] = 0;
    __syncthreads();

    // ---------- Phase 1: scan OWN contiguous chunk of cls_id_map ----------
    // Block bid owns int4 elements [bid*CH4, (bid+1)*CH4) -> positions are LOCAL,
    // no cross-block compaction, no grid barrier needed.
    for (int q = tid; q < CH4; q += 256) {
        int i = bid * CH4 + q;
        int4 v = cmap[i];
        int b4 = i * 4;
        if (v.x == 0) { int k = atomicAdd(&lc_s[0],1); if (k < MAXM) pos_s[0][k] = b4+0; }
        else if (v.x == 1) { int k = atomicAdd(&lc_s[1],1); if (k < MAXM) pos_s[1][k] = b4+0; }
        if (v.y == 0) { int k = atomicAdd(&lc_s[0],1); if (k < MAXM) pos_s[0][k] = b4+1; }
        else if (v.y == 1) { int k = atomicAdd(&lc_s[1],1); if (k < MAXM) pos_s[1][k] = b4+1; }
        if (v.z == 0) { int k = atomicAdd(&lc_s[0],1); if (k < MAXM) pos_s[0][k] = b4+2; }
        else if (v.z == 1) { int k = atomicAdd(&lc_s[1],1); if (k < MAXM) pos_s[1][k] = b4+2; }
        if (v.w == 0) { int k = atomicAdd(&lc_s[0],1); if (k < MAXM) pos_s[0][k] = b4+3; }
        else if (v.w == 1) { int k = atomicAdd(&lc_s[1],1); if (k < MAXM) pos_s[1][k] = b4+3; }
    }
    __syncthreads();
    int lc0 = lc_s[0] < MAXM ? lc_s[0] : MAXM;
    int lc1 = lc_s[1] < MAXM ? lc_s[1] : MAXM;
    if (tid == 0  && lc_s[0] > 0) atomicAdd(wsi + 8, lc_s[0]);
    if (tid == 64 && lc_s[1] > 0) atomicAdd(wsi + 9, lc_s[1]);

    // ---------- Phase 2: focal loss (grid-stride, all blocks) ----------
    {
        float pos = 0.f, neg = 0.f, cnt = 0.f;
        for (int i = bid * 256 + tid; i < n4; i += GRID * 256) {
            float4 x = hp[i];
            float4 g = gt[i];
            float xs[4] = {x.x, x.y, x.z, x.w};
            float gs[4] = {g.x, g.y, g.z, g.w};
            #pragma unroll
            for (int j = 0; j < 4; ++j) {
                float s = 1.f / (1.f + __expf(-xs[j]));
                s = fminf(fmaxf(s, 1e-4f), 1.f - 1e-4f);
                float gv = gs[j];
                if (gv == 1.f) {
                    float om = 1.f - s;
                    pos += __logf(s) * om * om;
                    cnt += 1.f;
                } else {
                    float nw = 1.f - gv; nw = nw * nw; nw = nw * nw;
                    neg += __logf(1.f - s) * s * s * nw;
                }
            }
        }
        float a = wave_sum(pos), b = wave_sum(neg), c = wave_sum(cnt);
        int lane = tid & 63, wid = tid >> 6;
        if (lane == 0) { sm[0][wid] = a; sm[1][wid] = b; sm[2][wid] = c; }
        __syncthreads();
        if (tid == 0) {
            float s0 = 0, s1 = 0, s2 = 0;
            #pragma unroll
            for (int w = 0; w < 4; ++w) { s0 += sm[0][w]; s1 += sm[1][w]; s2 += sm[2][w]; }
            atomicAdd(wsf + 0, s0);
            atomicAdd(wsf + 1, s1);
            atomicAdd(wsf + 2, s2);
        }
    }

    // ---------- Phase 3: wh/off L1 (block 0 only) ----------
    if (bid == 0) {
        __syncthreads();   // protect sm reuse
        float nwh = 0.f, noff = 0.f, msum = 0.f;
        for (int t = tid; t < BB * KOBJ; t += 256) {
            int b = t / KOBJ;
            float m = mask[t];
            int id = ind[t];
            const float* wp = wh_pred + (size_t)b * 2 * HW;
            const float* rp = reg_pred + (size_t)b * 2 * HW;
            float p0 = wp[id], p1 = wp[HW + id];
            float q0 = rp[id], q1 = rp[HW + id];
            float t0 = wh[t * 2], t1 = wh[t * 2 + 1];
            float r0 = reg[t * 2], r1 = reg[t * 2 + 1];
            nwh  += fabsf(p0 * m - t0 * m) + fabsf(p1 * m - t1 * m);
            noff += fabsf(q0 * m - r0 * m) + fabsf(q1 * m - r1 * m);
            msum += m;
        }
        float a = wave_sum(nwh), b = wave_sum(noff), c = wave_sum(msum);
        int lane = tid & 63, wid = tid >> 6;
        if (lane == 0) { sm[0][wid] = a; sm[1][wid] = b; sm[2][wid] = c; }
        __syncthreads();
        if (tid == 0) {
            float s0 = 0, s1 = 0, s2 = 0;
            #pragma unroll
            for (int w = 0; w < 4; ++w) { s0 += sm[0][w]; s1 += sm[1][w]; s2 += sm[2][w]; }
            atomicAdd(wsf + 3, s0);
            atomicAdd(wsf + 4, s1);
            atomicAdd(wsf + 5, s2);
        }
    }

    // ---------- Phase 4: reid CE on LOCAL matches (tiles of TE) ----------
    #pragma unroll
    for (int cls = 0; cls < 2; ++cls) {
        const int nid = cls ? NID1 : NID0;
        const float* Wc = cls ? W1 : W0;
        const float* bc = cls ? b1 : b0;
        const float escale = cls ? esc1 : esc0;
        const int lc = cls ? lc1 : lc0;
        const int* pp = pos_s[cls];
        float nll_loc = 0.f;

        for (int t0 = 0; t0 < lc; t0 += TE) {
            int ne = lc - t0; if (ne > TE) ne = TE;
            __syncthreads();   // prev tile's LDS readers done

            // gather: 16 threads per entry, 8 channels each
            {
                int e  = tid >> 4;
                int cg = tid & 15;
                if (tid < TE * 16) {
                    if (e < ne) {
                        int p = pp[t0 + e];
                        int b = p / HW, hw = p - b * HW;
                        const float* src = id_pred + (size_t)b * EMBD * HW + hw;
                        float f[8];
                        float ss = 0.f;
                        #pragma unroll
                        for (int j = 0; j < 8; ++j) {
                            f[j] = src[(size_t)(cg * 8 + j) * HW];
                            ss += f[j] * f[j];
                        }
                        #pragma unroll
                        for (int o = 1; o < 16; o <<= 1) ss += __shfl_xor(ss, o, 64);
                        float scale = escale / fmaxf(__builtin_sqrtf(ss), 1e-12f);
                        float4* dst = (float4*)&emb_s[e][cg * 8];
                        dst[0] = make_float4(f[0]*scale, f[1]*scale, f[2]*scale, f[3]*scale);
                        dst[1] = make_float4(f[4]*scale, f[5]*scale, f[6]*scale, f[7]*scale);
                    } else {
                        float4* dst = (float4*)&emb_s[e][cg * 8];
                        dst[0] = make_float4(0.f, 0.f, 0.f, 0.f);
                        dst[1] = make_float4(0.f, 0.f, 0.f, 0.f);
                    }
                }
                if (tid < TE) {
                    int tg = -1;
                    if (tid < ne) {
                        int p = pp[t0 + tid];
                        int b = p / HW, hw = p - b * HW;
                        tg = cls_tr[((size_t)b * 2 + cls) * HW + hw];
                    }
                    tgt_s[tid] = tg;
                    tgtl_s[tid] = 0.f;
                }
            }
            __syncthreads();

            // logits rows r0 = tid (tid < 256 <= nid always valid), r1 = tid+256
            int r0 = tid, r1 = tid + 256;
            bool v1ok = r1 < nid;
            const float4* wr0 = (const float4*)(Wc + (size_t)r0 * EMBD);
            const float4* wr1 = (const float4*)(Wc + (size_t)(v1ok ? r1 : 0) * EMBD);

            float acc0[TE], acc1[TE];
            #pragma unroll
            for (int e = 0; e < TE; ++e) { acc0[e] = 0.f; acc1[e] = 0.f; }

            for (int j = 0; j < EMBD / 4; ++j) {
                float4 w0 = wr0[j];
                float4 w1 = wr1[j];
                #pragma unroll
                for (int e = 0; e < TE; ++e) {
                    float4 em = ((const float4*)emb_s[e])[j];   // wave-broadcast LDS read
                    acc0[e] = fmaf(w0.x, em.x, fmaf(w0.y, em.y, fmaf(w0.z, em.z, fmaf(w0.w, em.w, acc0[e]))));
                    acc1[e] = fmaf(w1.x, em.x, fmaf(w1.y, em.y, fmaf(w1.z, em.z, fmaf(w1.w, em.w, acc1[e]))));
                }
            }
            float bias0 = bc[r0];
            float bias1 = v1ok ? bc[r1] : 0.f;
            #pragma unroll
            for (int e = 0; e < TE; ++e) {
                acc0[e] += bias0;
                acc1[e] = v1ok ? (acc1[e] + bias1) : -1e30f;
                if (r0 == tgt_s[e]) tgtl_s[e] = acc0[e];
                if (v1ok && r1 == tgt_s[e]) tgtl_s[e] = acc1[e];
            }

            int lane = tid & 63, wid = tid >> 6;

            float mx[TE];
            #pragma unroll
            for (int e = 0; e < TE; ++e) mx[e] = fmaxf(acc0[e], acc1[e]);
            #pragma unroll
            for (int o = 32; o > 0; o >>= 1) {
                #pragma unroll
                for (int e = 0; e < TE; ++e) mx[e] = fmaxf(mx[e], __shfl_xor(mx[e], o, 64));
            }
            if (lane == 0) {
                #pragma unroll
                for (int e = 0; e < TE; ++e) red_m[e][wid] = mx[e];
            }
            __syncthreads();
            float bm[TE];
            #pragma unroll
            for (int e = 0; e < TE; ++e)
                bm[e] = fmaxf(fmaxf(red_m[e][0], red_m[e][1]), fmaxf(red_m[e][2], red_m[e][3]));

            float se[TE];
            #pragma unroll
            for (int e = 0; e < TE; ++e) se[e] = __expf(acc0[e] - bm[e]) + __expf(acc1[e] - bm[e]);
            #pragma unroll
            for (int o = 32; o > 0; o >>= 1) {
                #pragma unroll
                for (int e = 0; e < TE; ++e) se[e] += __shfl_xor(se[e], o, 64);
            }
            if (lane == 0) {
                #pragma unroll
                for (int e = 0; e < TE; ++e) red_s[e][wid] = se[e];
            }
            __syncthreads();

            if (tid == 0) {
                #pragma unroll
                for (int e = 0; e < TE; ++e) {
                    if (e < ne) {
                        float S = red_s[e][0] + red_s[e][1] + red_s[e][2] + red_s[e][3];
                        nll_loc += bm[e] + __logf(S) - tgtl_s[e];
                    }
                }
            }
        }
        if (tid == 0 && lc > 0) atomicAdd(wsf + 6 + cls, nll_loc);
    }

    // ---------- done-counter: last block runs final combine ----------
    __syncthreads();
    if (tid == 0) {
        int old = __hip_atomic_fetch_add(wsi + 10, 1, __ATOMIC_ACQ_REL,
                                         __HIP_MEMORY_SCOPE_AGENT);
        if (old == GRID - 1)
            final_combine(wsf, sdet, sid, out);
    }
}

extern "C" void kernel_launch(void* const* d_in, const int* in_sizes, int n_in,
                              void* d_out, int out_size, void* d_ws, size_t ws_size,
                              hipStream_t stream) {
    const float* hm_pred   = (const float*)d_in[0];
    const float* wh_pred   = (const float*)d_in[1];
    const float* reg_pred  = (const float*)d_in[2];
    const float* id_pred   = (const float*)d_in[3];
    const float* hm        = (const float*)d_in[4];
    const float* wh        = (const float*)d_in[5];
    const float* reg       = (const float*)d_in[6];
    const float* reg_mask  = (const float*)d_in[7];
    const int*   ind       = (const int*)d_in[8];
    const int*   cls_map   = (const int*)d_in[9];
    const int*   cls_tr    = (const int*)d_in[10];
    const float* W0        = (const float*)d_in[11];
    const float* b0        = (const float*)d_in[12];
    const float* W1        = (const float*)d_in[13];
    const float* b1        = (const float*)d_in[14];
    const float* s_det     = (const float*)d_in[15];
    const float* s_id      = (const float*)d_in[16];

    float* wsf = (float*)d_ws;

    // zero the 16-word accumulator/done-counter header each call
    hipMemsetAsync(d_ws, 0, 64, stream);

    const int n4 = (BB * HMC * HW) / 4;   // 165376
    const float esc0 = (float)(sqrt(2.0) * log((double)NID0 - 1.0));
    const float esc1 = (float)(sqrt(2.0) * log((double)NID1 - 1.0));

    mega_kernel<<<GRID, 256, 0, stream>>>(
        (const float4*)hm_pred, (const float4*)hm, (const int4*)cls_map,
        wh_pred, reg_pred, wh, reg, reg_mask, ind,
        id_pred, cls_tr, W0, b0, W1, b1, s_det, s_id,
        wsf, (float*)d_out, esc0, esc1, n4);
}